// Round 5
// baseline (433.597 us; speedup 1.0000x reference)
//
#include <hip/hip_runtime.h>

// Problem constants: B=4, S=2048 -> T=8192 tokens; H=512, F=2048, E=8, K=2.
#define T_TOKENS 8192
#define HD 512
#define FD 2048
#define NE 8
#define CAP 8192   // per-expert bucket capacity
#define CSTRIDE 32 // counter padding: one counter per 128B line

#define BM 128
// BK = 64 (8 chunks of 8 bf16 per row); BN template param (128 FC1 / 64 FC2)

typedef __attribute__((ext_vector_type(8))) short short8;   // 8 bf16 = 4 VGPRs
typedef __attribute__((ext_vector_type(4))) float f32x4;    // MFMA accumulator

__device__ __forceinline__ ushort f2bf(float f) {
  union { float f; unsigned u; } v; v.f = f;
  unsigned u = v.u;
  return (ushort)((u + 0x7fffu + ((u >> 16) & 1u)) >> 16);  // RNE
}

// async global->LDS, 16B per lane. HW semantics: wave-uniform LDS base +
// lane*16. Our per-thread pointer is exactly base(s)*1024 + lane*16.
__device__ __forceinline__ void gld16(const void* g, void* l) {
  __builtin_amdgcn_global_load_lds(
      (const __attribute__((address_space(1))) void*)g,
      (__attribute__((address_space(3))) void*)l, 16, 0, 0);
}

// ---------------- fp32 -> bf16 bulk convert ----------------
__global__ void cvt_bf16(const float4* __restrict__ src, ushort4* __restrict__ dst, int n4) {
  int i = blockIdx.x * blockDim.x + threadIdx.x;
  int st = gridDim.x * blockDim.x;
  for (; i < n4; i += st) {
    float4 v = src[i];
    ushort4 o;
    o.x = f2bf(v.x); o.y = f2bf(v.y); o.z = f2bf(v.z); o.w = f2bf(v.w);
    dst[i] = o;
  }
}

// ---------------- router: logits -> softmax -> top2 -> buckets ----------------
#define TPW 16
__global__ void router_kernel(const float* __restrict__ x, const float* __restrict__ rw,
                              float* __restrict__ probs_out, float* __restrict__ topk_out,
                              int* __restrict__ counts, int* __restrict__ bucket_tok,
                              float* __restrict__ bucket_w, int4* __restrict__ tok_info) {
  __shared__ int lcnt[NE];
  __shared__ int lbase[NE];
  __shared__ int ls_e0[64], ls_e1[64], ls_s0[64], ls_s1[64];
  __shared__ float ls_w0[64], ls_w1[64];

  int wave = threadIdx.x >> 6, lane = threadIdx.x & 63;
  if (threadIdx.x < NE) lcnt[threadIdx.x] = 0;
  __syncthreads();

  int tbase = blockIdx.x * 64;
  for (int it = 0; it < TPW; it++) {
    int lt = wave * TPW + it;
    int t = tbase + lt;
    float acc[NE];
#pragma unroll
    for (int e = 0; e < NE; e++) acc[e] = 0.f;
    const float* xr = x + (size_t)t * HD;
    for (int c = 0; c < HD; c += 64) {
      float xv = xr[c + lane];
#pragma unroll
      for (int e = 0; e < NE; e++) acc[e] += xv * rw[e * HD + c + lane];
    }
#pragma unroll
    for (int e = 0; e < NE; e++) {
#pragma unroll
      for (int s = 32; s > 0; s >>= 1) acc[e] += __shfl_xor(acc[e], s, 64);
    }
    if (lane == 0) {
      float m = acc[0];
#pragma unroll
      for (int e = 1; e < NE; e++) m = fmaxf(m, acc[e]);
      float p[NE], s = 0.f;
#pragma unroll
      for (int e = 0; e < NE; e++) { p[e] = expf(acc[e] - m); s += p[e]; }
      float inv = 1.f / s;
#pragma unroll
      for (int e = 0; e < NE; e++) { p[e] *= inv; probs_out[(size_t)t * NE + e] = p[e]; }
      int i0 = 0;
#pragma unroll
      for (int e = 1; e < NE; e++) if (p[e] > p[i0]) i0 = e;
      int i1 = (i0 == 0) ? 1 : 0;
#pragma unroll
      for (int e = 0; e < NE; e++) if (e != i0 && p[e] > p[i1]) i1 = e;
      float r = 1.f / (p[i0] + p[i1] + 1e-9f);
      topk_out[(size_t)t * 2 + 0] = (float)i0;
      topk_out[(size_t)t * 2 + 1] = (float)i1;
      ls_e0[lt] = i0; ls_e1[lt] = i1;
      ls_w0[lt] = p[i0] * r; ls_w1[lt] = p[i1] * r;
      ls_s0[lt] = atomicAdd(&lcnt[i0], 1);
      ls_s1[lt] = atomicAdd(&lcnt[i1], 1);
    }
  }
  __syncthreads();
  if (threadIdx.x < NE)
    lbase[threadIdx.x] = atomicAdd(&counts[threadIdx.x * CSTRIDE], lcnt[threadIdx.x]);
  __syncthreads();
  if (threadIdx.x < 64) {
    int lt = threadIdx.x, t = tbase + lt;
    int e0 = ls_e0[lt], e1 = ls_e1[lt];
    int g0 = lbase[e0] + ls_s0[lt];
    int g1 = lbase[e1] + ls_s1[lt];
    bucket_tok[e0 * CAP + g0] = t; bucket_w[e0 * CAP + g0] = ls_w0[lt];
    bucket_tok[e1 * CAP + g1] = t; bucket_w[e1 * CAP + g1] = ls_w1[lt];
    tok_info[t] = make_int4(e0, e1, g0, g1);
  }
}

__global__ void scan_kernel(const int* __restrict__ counts, int* __restrict__ offsets) {
  if (threadIdx.x == 0) {
    int o = 0;
#pragma unroll
    for (int e = 0; e < NE; e++) { offsets[e] = o; o += counts[e * CSTRIDE]; }
  }
}

// ---------------- grouped GEMM (bf16 MFMA 16x16x32), FC1 and FC2 ----------------
// R5: global_load_lds width=16 staging into KC-MAJOR LDS layout [kc][row]:
// chunk (kc,row) at byte (kc*ROWS + row)*16. DMA constraint satisfied
// (chunk = s*64 + lane, s wave-uniform); fragment reads are lane-consecutive
// 16B -> conflict-free (R3's [row][BK] layout cost 4.3M conflict cycles).
// BK=64 halves barrier drains vs R3. Weights pre-converted to bf16 (R4's
// in-loop fp32 B doubled FETCH_SIZE on a 16x re-read operand: 294 MB, -21%).
template <int BN_, bool IS_FC1>
__global__ __launch_bounds__(256, 2)
void ffn_gemm(const ushort* __restrict__ Ab, const ushort* __restrict__ Bw,
              const float* __restrict__ bias, const int* __restrict__ counts,
              const int* __restrict__ offsets, const int* __restrict__ bucket_tok,
              const float* __restrict__ bucket_w, ushort* __restrict__ Aout,
              float* __restrict__ Yout, int KD, int ND) {
  constexpr int JW = BN_ / 32;     // j-tiles per wave: 4 (FC1) / 2 (FC2)
  constexpr int BISS = BN_ / 32;   // B staging issues per thread: 4 / 2

  int e = blockIdx.z;
  int cnt = counts[e * CSTRIDE];
  int m0 = blockIdx.y * BM;
  if (m0 >= cnt) return;
  int n0 = blockIdx.x * BN_;
  int off = offsets[e];

  __shared__ alignas(16) ushort As[8 * BM * 8];    // 16 KB  [kc][row][8]
  __shared__ alignas(16) ushort Bs[8 * BN_ * 8];   // 16 / 8 KB

  int tid = threadIdx.x;
  int wid = tid >> 6, lane = tid & 63;
  int wm = wid >> 1, wn = wid & 1;
  int q = lane >> 4, l16 = lane & 15;

  // ---- staging maps: issue s = u*4 + wid; chunk index = s*64 + lane ----
  const ushort* agp[4];
  ushort* alp[4];
#pragma unroll
  for (int u = 0; u < 4; u++) {
    int s = u * 4 + wid;
    int kc = s >> 1, m = ((s & 1) << 6) + lane;   // chunk = kc*128 + m = s*64+lane
    int mr = min(m0 + m, cnt - 1);
    int arow = IS_FC1 ? bucket_tok[e * CAP + mr] : (off + mr);
    agp[u] = Ab + (size_t)arow * KD + kc * 8;
    alp[u] = As + (size_t)(s * 64 + lane) * 8;
  }
  const ushort* bgp[BISS];
  ushort* blp[BISS];
#pragma unroll
  for (int u = 0; u < BISS; u++) {
    int s = u * 4 + wid;
    int kc, n;
    if (BN_ == 128) { kc = s >> 1; n = ((s & 1) << 6) + lane; }
    else            { kc = s;      n = lane; }
    bgp[u] = Bw + ((size_t)e * ND + n0 + n) * KD + kc * 8;
    blp[u] = Bs + (size_t)(s * 64 + lane) * 8;
  }

  f32x4 acc[4][JW] = {};

  for (int k0 = 0; k0 < KD; k0 += 64) {
#pragma unroll
    for (int u = 0; u < 4; u++) gld16(agp[u] + k0, alp[u]);
#pragma unroll
    for (int u = 0; u < BISS; u++) gld16(bgp[u] + k0, blp[u]);
    __syncthreads();
#pragma unroll
    for (int t = 0; t < 2; t++) {
      int kcc = t * 4 + q;
      short8 af[4], bfr[JW];
#pragma unroll
      for (int i = 0; i < 4; i++)
        af[i] = *(const short8*)&As[(kcc * BM + wm * 64 + i * 16 + l16) * 8];
#pragma unroll
      for (int j = 0; j < JW; j++)
        bfr[j] = *(const short8*)&Bs[(kcc * BN_ + wn * (16 * JW) + j * 16 + l16) * 8];
#pragma unroll
      for (int i = 0; i < 4; i++)
#pragma unroll
        for (int j = 0; j < JW; j++)
          acc[i][j] = __builtin_amdgcn_mfma_f32_16x16x32_bf16(af[i], bfr[j], acc[i][j], 0, 0, 0);
    }
    __syncthreads();
  }

  // ---- epilogue through LDS (reuses As region) ----
  float bcol[JW];
#pragma unroll
  for (int j = 0; j < JW; j++)
    bcol[j] = bias[(size_t)e * ND + n0 + wn * (16 * JW) + j * 16 + l16];

  if (IS_FC1) {
    ushort* Ct = As;  // [32][136] bf16 = 8704 B
#pragma unroll
    for (int i = 0; i < 4; i++) {
      __syncthreads();
#pragma unroll
      for (int j = 0; j < JW; j++)
#pragma unroll
        for (int r = 0; r < 4; r++) {
          float v = acc[i][j][r] + bcol[j];
          float g = 0.5f * v * (1.0f + erff(v * 0.70710678118654752f));
          Ct[(wm * 16 + q * 4 + r) * 136 + wn * 64 + j * 16 + l16] = f2bf(g);
        }
      __syncthreads();
#pragma unroll
      for (int u = 0; u < 2; u++) {
        int c = tid + u * 256;            // 512 chunks of 8 bf16
        int ml = c >> 4, cc = c & 15;
        int gm = m0 + (ml >> 4) * 64 + i * 16 + (ml & 15);
        if (gm < cnt)
          *(uint4*)&Aout[(size_t)(off + gm) * ND + n0 + cc * 8] =
              *(const uint4*)&Ct[ml * 136 + cc * 8];
      }
    }
  } else {
    float* Ct = (float*)As;  // [32][68] fp32 = 8704 B
#pragma unroll
    for (int i = 0; i < 4; i++) {
      __syncthreads();
#pragma unroll
      for (int r = 0; r < 4; r++) {
        int gm = m0 + wm * 64 + i * 16 + q * 4 + r;
        float wgt = bucket_w[e * CAP + min(gm, cnt - 1)];
#pragma unroll
        for (int j = 0; j < JW; j++)
          Ct[(wm * 16 + q * 4 + r) * 68 + wn * 32 + j * 16 + l16] = wgt * (acc[i][j][r] + bcol[j]);
      }
      __syncthreads();
#pragma unroll
      for (int u = 0; u < 2; u++) {
        int c = tid + u * 256;            // 512 chunks of 4 floats (32 rows x 64 cols)
        int ml = c >> 4, cc = c & 15;
        int gm = m0 + (ml >> 4) * 64 + i * 16 + (ml & 15);
        if (gm < cnt)
          *(float4*)&Yout[(size_t)(off + gm) * ND + n0 + cc * 4] =
              *(const float4*)&Ct[ml * 68 + cc * 4];
      }
    }
  }
}

// ---------------- combine: out[t] = Y[row(e0,s0)] + Y[row(e1,s1)] ----------------
__global__ void combine_kernel(const float4* __restrict__ Y, const int4* __restrict__ tok_info,
                               const int* __restrict__ offsets, float4* __restrict__ out) {
  int t = blockIdx.x;
  int4 ti = tok_info[t];
  int g0 = offsets[ti.x] + ti.z;
  int g1 = offsets[ti.y] + ti.w;
  int i = threadIdx.x;  // 128 threads, H/4 = 128 float4 per row
  float4 a = Y[(size_t)g0 * (HD / 4) + i];
  float4 b = Y[(size_t)g1 * (HD / 4) + i];
  out[(size_t)t * (HD / 4) + i] = make_float4(a.x + b.x, a.y + b.y, a.z + b.z, a.w + b.w);
}

extern "C" void kernel_launch(void* const* d_in, const int* in_sizes, int n_in,
                              void* d_out, int out_size, void* d_ws, size_t ws_size,
                              hipStream_t stream) {
  const float* x    = (const float*)d_in[0];
  const float* rw   = (const float*)d_in[1];
  const float* fc1w = (const float*)d_in[2];
  const float* fc1b = (const float*)d_in[3];
  const float* fc2w = (const float*)d_in[4];
  const float* fc2b = (const float*)d_in[5];

  float* out   = (float*)d_out;
  float* probs = out + (size_t)T_TOKENS * HD;
  float* topk  = probs + (size_t)T_TOKENS * NE;

  char* p = (char*)d_ws;
  auto carve = [&](size_t bytes) { char* r = p; p += (bytes + 255) & ~(size_t)255; return r; };
  int*    counts     = (int*)carve(NE * CSTRIDE * sizeof(int));
  int*    offsets    = (int*)carve(NE * sizeof(int));
  int*    bucket_tok = (int*)carve((size_t)NE * CAP * sizeof(int));
  float*  bucket_w   = (float*)carve((size_t)NE * CAP * sizeof(float));
  int4*   tok_info   = (int4*)carve((size_t)T_TOKENS * sizeof(int4));
  ushort* xb   = (ushort*)carve((size_t)T_TOKENS * HD * 2);
  ushort* w1b  = (ushort*)carve((size_t)NE * FD * HD * 2);
  ushort* w2b  = (ushort*)carve((size_t)NE * HD * FD * 2);
  ushort* Abuf = (ushort*)carve((size_t)T_TOKENS * 2 * FD * 2);  // compact GELU out, bf16
  float*  Y    = (float*)carve((size_t)T_TOKENS * 2 * HD * 4);   // gated FC2 rows, fp32

  hipMemsetAsync(counts, 0, NE * CSTRIDE * sizeof(int), stream);
  cvt_bf16<<<2048, 256, 0, stream>>>((const float4*)x, (ushort4*)xb, T_TOKENS * HD / 4);
  cvt_bf16<<<2048, 256, 0, stream>>>((const float4*)fc1w, (ushort4*)w1b, NE * FD * HD / 4);
  cvt_bf16<<<2048, 256, 0, stream>>>((const float4*)fc2w, (ushort4*)w2b, NE * HD * FD / 4);
  router_kernel<<<T_TOKENS / 64, 256, 0, stream>>>(x, rw, probs, topk, counts, bucket_tok,
                                                   bucket_w, tok_info);
  scan_kernel<<<1, 64, 0, stream>>>(counts, offsets);
  ffn_gemm<128, true><<<dim3(FD / 128, CAP / BM, NE), 256, 0, stream>>>(
      xb, w1b, fc1b, counts, offsets, bucket_tok, bucket_w, Abuf, nullptr, HD, FD);
  ffn_gemm<64, false><<<dim3(HD / 64, CAP / BM, NE), 256, 0, stream>>>(
      Abuf, w2b, fc2b, counts, offsets, bucket_tok, bucket_w, nullptr, Y, FD, HD);
  combine_kernel<<<T_TOKENS, 128, 0, stream>>>((const float4*)Y, tok_info, offsets, (float4*)out);
}

// Round 6
// 415.297 us; speedup vs baseline: 1.0441x; 1.0441x over previous
//
#include <hip/hip_runtime.h>

// Problem constants: B=4, S=2048 -> T=8192 tokens; H=512, F=2048, E=8, K=2.
#define T_TOKENS 8192
#define HD 512
#define FD 2048
#define NE 8
#define CAP 8192   // per-expert bucket capacity
#define CSTRIDE 32 // counter padding: one counter per 128B line

#define BM 128
#define BN 128
#define BK 32      // R5's BK=64/BN=64 doubled FC2 A-refetch (296 MB) -> revert

typedef __attribute__((ext_vector_type(8))) short short8;   // 8 bf16 = 4 VGPRs
typedef __attribute__((ext_vector_type(4))) float f32x4;    // MFMA accumulator

__device__ __forceinline__ ushort f2bf(float f) {
  union { float f; unsigned u; } v; v.f = f;
  unsigned u = v.u;
  return (ushort)((u + 0x7fffu + ((u >> 16) & 1u)) >> 16);  // RNE
}

// async global->LDS, 16B per lane (wave-uniform base + lane*16).
__device__ __forceinline__ void gld16(const void* g, void* l) {
  __builtin_amdgcn_global_load_lds(
      (const __attribute__((address_space(1))) void*)g,
      (__attribute__((address_space(3))) void*)l, 16, 0, 0);
}

// ---------------- fp32 -> bf16 bulk convert ----------------
__global__ void cvt_bf16(const float4* __restrict__ src, ushort4* __restrict__ dst, int n4) {
  int i = blockIdx.x * blockDim.x + threadIdx.x;
  int st = gridDim.x * blockDim.x;
  for (; i < n4; i += st) {
    float4 v = src[i];
    ushort4 o;
    o.x = f2bf(v.x); o.y = f2bf(v.y); o.z = f2bf(v.z); o.w = f2bf(v.w);
    dst[i] = o;
  }
}

// ---------------- router: logits -> softmax -> top2 -> buckets ----------------
#define TPW 16
__global__ void router_kernel(const float* __restrict__ x, const float* __restrict__ rw,
                              float* __restrict__ probs_out, float* __restrict__ topk_out,
                              int* __restrict__ counts, int* __restrict__ bucket_tok,
                              float* __restrict__ bucket_w, int4* __restrict__ tok_info) {
  __shared__ int lcnt[NE];
  __shared__ int lbase[NE];
  __shared__ int ls_e0[64], ls_e1[64], ls_s0[64], ls_s1[64];
  __shared__ float ls_w0[64], ls_w1[64];

  int wave = threadIdx.x >> 6, lane = threadIdx.x & 63;
  if (threadIdx.x < NE) lcnt[threadIdx.x] = 0;
  __syncthreads();

  int tbase = blockIdx.x * 64;
  for (int it = 0; it < TPW; it++) {
    int lt = wave * TPW + it;
    int t = tbase + lt;
    float acc[NE];
#pragma unroll
    for (int e = 0; e < NE; e++) acc[e] = 0.f;
    const float* xr = x + (size_t)t * HD;
    for (int c = 0; c < HD; c += 64) {
      float xv = xr[c + lane];
#pragma unroll
      for (int e = 0; e < NE; e++) acc[e] += xv * rw[e * HD + c + lane];
    }
#pragma unroll
    for (int e = 0; e < NE; e++) {
#pragma unroll
      for (int s = 32; s > 0; s >>= 1) acc[e] += __shfl_xor(acc[e], s, 64);
    }
    if (lane == 0) {
      float m = acc[0];
#pragma unroll
      for (int e = 1; e < NE; e++) m = fmaxf(m, acc[e]);
      float p[NE], s = 0.f;
#pragma unroll
      for (int e = 0; e < NE; e++) { p[e] = expf(acc[e] - m); s += p[e]; }
      float inv = 1.f / s;
#pragma unroll
      for (int e = 0; e < NE; e++) { p[e] *= inv; probs_out[(size_t)t * NE + e] = p[e]; }
      int i0 = 0;
#pragma unroll
      for (int e = 1; e < NE; e++) if (p[e] > p[i0]) i0 = e;
      int i1 = (i0 == 0) ? 1 : 0;
#pragma unroll
      for (int e = 0; e < NE; e++) if (e != i0 && p[e] > p[i1]) i1 = e;
      float r = 1.f / (p[i0] + p[i1] + 1e-9f);
      topk_out[(size_t)t * 2 + 0] = (float)i0;
      topk_out[(size_t)t * 2 + 1] = (float)i1;
      ls_e0[lt] = i0; ls_e1[lt] = i1;
      ls_w0[lt] = p[i0] * r; ls_w1[lt] = p[i1] * r;
      ls_s0[lt] = atomicAdd(&lcnt[i0], 1);
      ls_s1[lt] = atomicAdd(&lcnt[i1], 1);
    }
  }
  __syncthreads();
  if (threadIdx.x < NE)
    lbase[threadIdx.x] = atomicAdd(&counts[threadIdx.x * CSTRIDE], lcnt[threadIdx.x]);
  __syncthreads();
  if (threadIdx.x < 64) {
    int lt = threadIdx.x, t = tbase + lt;
    int e0 = ls_e0[lt], e1 = ls_e1[lt];
    int g0 = lbase[e0] + ls_s0[lt];
    int g1 = lbase[e1] + ls_s1[lt];
    bucket_tok[e0 * CAP + g0] = t; bucket_w[e0 * CAP + g0] = ls_w0[lt];
    bucket_tok[e1 * CAP + g1] = t; bucket_w[e1 * CAP + g1] = ls_w1[lt];
    tok_info[t] = make_int4(e0, e1, g0, g1);
  }
}

__global__ void scan_kernel(const int* __restrict__ counts, int* __restrict__ offsets) {
  if (threadIdx.x == 0) {
    int o = 0;
#pragma unroll
    for (int e = 0; e < NE; e++) { offsets[e] = o; o += counts[e * CSTRIDE]; }
  }
}

// ---------------- grouped GEMM (bf16 MFMA 16x16x32), FC1 and FC2 ----------------
// R6: BK=32, BN=128 (R3 fetch profile) + kc-major conflict-free LDS (R5)
// + double-buffered LDS with AITER-style pipeline: issue tile k+1 DMAs,
// then `s_waitcnt vmcnt(4)` (NOT 0) + s_barrier -> 4 DMAs stay in flight
// across the barrier and the MFMA block. Inline asm avoids __syncthreads'
// compiler-forced vmcnt(0) drain (the ~20% structural stall, m97 analysis).
// LDS layout: chunk (kc,row) at byte (kc*128+row)*16; chunk index == u*256+tid
// satisfies the DMA wave-uniform-base+lane*16 constraint; fragment reads are
// lane-consecutive 16B (R5-verified: 131K conflict cycles ~ zero).
template <bool IS_FC1>
__global__ __launch_bounds__(256, 3)
void ffn_gemm(const ushort* __restrict__ Ab, const ushort* __restrict__ Bw,
              const float* __restrict__ bias, const int* __restrict__ counts,
              const int* __restrict__ offsets, const int* __restrict__ bucket_tok,
              const float* __restrict__ bucket_w, ushort* __restrict__ Aout,
              float* __restrict__ Yout, int KD, int ND) {
  int e = blockIdx.z;
  int cnt = counts[e * CSTRIDE];
  int m0 = blockIdx.y * BM;
  if (m0 >= cnt) return;
  int n0 = blockIdx.x * BN;
  int off = offsets[e];

  // [A0 8K][B0 8K][A1 8K][B1 8K] = 32 KB (4096 ushorts each)
  __shared__ alignas(16) ushort smem[16384];

  int tid = threadIdx.x;
  int wid = tid >> 6, lane = tid & 63;
  int wm = wid >> 1, wn = wid & 1;
  int q = lane >> 4, l16 = lane & 15;

  // staging: chunk c = u*256 + tid; kc = u*2 + (tid>>7), row = tid&127
  int srow = tid & 127;
  int kc0 = tid >> 7;
  int mr = min(m0 + srow, cnt - 1);
  int arow = IS_FC1 ? bucket_tok[e * CAP + mr] : (off + mr);
  const ushort* ag = Ab + (size_t)arow * KD + kc0 * 8;
  const ushort* bg = Bw + ((size_t)e * ND + n0 + srow) * KD + kc0 * 8;

  f32x4 acc[4][4] = {};
  const int nIter = KD / BK;

  // prologue: tile 0 -> buffer 0 (4 DMA issues/thread)
  {
    ushort* al = smem + (size_t)tid * 8;
    ushort* bl = smem + 4096 + (size_t)tid * 8;
    gld16(ag, al);      gld16(ag + 16, al + 2048);
    gld16(bg, bl);      gld16(bg + 16, bl + 2048);
  }

  for (int k = 0; k < nIter; k++) {
    int pr = k & 1;
    if (k + 1 < nIter) {
      int pw = pr ^ 1;
      const ushort* agn = ag + (size_t)(k + 1) * BK;
      const ushort* bgn = bg + (size_t)(k + 1) * BK;
      ushort* aln = smem + pw * 8192 + (size_t)tid * 8;
      ushort* bln = smem + pw * 8192 + 4096 + (size_t)tid * 8;
      gld16(agn, aln);      gld16(agn + 16, aln + 2048);
      gld16(bgn, bln);      gld16(bgn + 16, bln + 2048);
      // tile k's 4 DMAs (oldest) retired; tile k+1's 4 stay in flight
      asm volatile("s_waitcnt vmcnt(4)\ns_barrier" ::: "memory");
    } else {
      asm volatile("s_waitcnt vmcnt(0)\ns_barrier" ::: "memory");
    }
    const ushort* Ak = smem + pr * 8192;
    const ushort* Bk = Ak + 4096;
    short8 af[4], bfr[4];
#pragma unroll
    for (int i = 0; i < 4; i++)
      af[i] = *(const short8*)&Ak[(q * BM + wm * 64 + i * 16 + l16) * 8];
#pragma unroll
    for (int j = 0; j < 4; j++)
      bfr[j] = *(const short8*)&Bk[(q * BN + wn * 64 + j * 16 + l16) * 8];
#pragma unroll
    for (int i = 0; i < 4; i++)
#pragma unroll
      for (int j = 0; j < 4; j++)
        acc[i][j] = __builtin_amdgcn_mfma_f32_16x16x32_bf16(af[i], bfr[j], acc[i][j], 0, 0, 0);
    // all waves done reading buf pr before iter k+1 overwrites it
    asm volatile("s_barrier" ::: "memory");
  }

  // ---- epilogue through LDS (reuses smem) ----
  float bcol[4];
#pragma unroll
  for (int j = 0; j < 4; j++)
    bcol[j] = bias[(size_t)e * ND + n0 + wn * 64 + j * 16 + l16];

  if (IS_FC1) {
    ushort* Ct = smem;  // [32][136] bf16 = 8704 B
#pragma unroll
    for (int i = 0; i < 4; i++) {
      __syncthreads();
#pragma unroll
      for (int j = 0; j < 4; j++)
#pragma unroll
        for (int r = 0; r < 4; r++) {
          float v = acc[i][j][r] + bcol[j];
          float g = 0.5f * v * (1.0f + erff(v * 0.70710678118654752f));
          Ct[(wm * 16 + q * 4 + r) * 136 + wn * 64 + j * 16 + l16] = f2bf(g);
        }
      __syncthreads();
#pragma unroll
      for (int u = 0; u < 2; u++) {
        int c = tid + u * 256;            // 512 chunks of 8 bf16
        int ml = c >> 4, cc = c & 15;
        int gm = m0 + (ml >> 4) * 64 + i * 16 + (ml & 15);
        if (gm < cnt)
          *(uint4*)&Aout[(size_t)(off + gm) * ND + n0 + cc * 8] =
              *(const uint4*)&Ct[ml * 136 + cc * 8];
      }
    }
  } else {
    float* Ct = (float*)smem;  // [32][132] fp32 = 16896 B
#pragma unroll
    for (int i = 0; i < 4; i++) {
      __syncthreads();
#pragma unroll
      for (int r = 0; r < 4; r++) {
        int gm = m0 + wm * 64 + i * 16 + q * 4 + r;
        float wgt = bucket_w[e * CAP + min(gm, cnt - 1)];
#pragma unroll
        for (int j = 0; j < 4; j++)
          Ct[(wm * 16 + q * 4 + r) * 132 + wn * 64 + j * 16 + l16] = wgt * (acc[i][j][r] + bcol[j]);
      }
      __syncthreads();
#pragma unroll
      for (int u = 0; u < 4; u++) {
        int c = tid + u * 256;            // 1024 chunks of 4 floats
        int ml = c >> 5, cc = c & 31;
        int gm = m0 + (ml >> 4) * 64 + i * 16 + (ml & 15);
        if (gm < cnt)
          *(float4*)&Yout[(size_t)(off + gm) * ND + n0 + cc * 4] =
              *(const float4*)&Ct[ml * 132 + cc * 4];
      }
    }
  }
}

// ---------------- combine: out[t] = Y[row(e0,s0)] + Y[row(e1,s1)] ----------------
__global__ void combine_kernel(const float4* __restrict__ Y, const int4* __restrict__ tok_info,
                               const int* __restrict__ offsets, float4* __restrict__ out) {
  int t = blockIdx.x;
  int4 ti = tok_info[t];
  int g0 = offsets[ti.x] + ti.z;
  int g1 = offsets[ti.y] + ti.w;
  int i = threadIdx.x;  // 128 threads, H/4 = 128 float4 per row
  float4 a = Y[(size_t)g0 * (HD / 4) + i];
  float4 b = Y[(size_t)g1 * (HD / 4) + i];
  out[(size_t)t * (HD / 4) + i] = make_float4(a.x + b.x, a.y + b.y, a.z + b.z, a.w + b.w);
}

extern "C" void kernel_launch(void* const* d_in, const int* in_sizes, int n_in,
                              void* d_out, int out_size, void* d_ws, size_t ws_size,
                              hipStream_t stream) {
  const float* x    = (const float*)d_in[0];
  const float* rw   = (const float*)d_in[1];
  const float* fc1w = (const float*)d_in[2];
  const float* fc1b = (const float*)d_in[3];
  const float* fc2w = (const float*)d_in[4];
  const float* fc2b = (const float*)d_in[5];

  float* out   = (float*)d_out;
  float* probs = out + (size_t)T_TOKENS * HD;
  float* topk  = probs + (size_t)T_TOKENS * NE;

  char* p = (char*)d_ws;
  auto carve = [&](size_t bytes) { char* r = p; p += (bytes + 255) & ~(size_t)255; return r; };
  int*    counts     = (int*)carve(NE * CSTRIDE * sizeof(int));
  int*    offsets    = (int*)carve(NE * sizeof(int));
  int*    bucket_tok = (int*)carve((size_t)NE * CAP * sizeof(int));
  float*  bucket_w   = (float*)carve((size_t)NE * CAP * sizeof(float));
  int4*   tok_info   = (int4*)carve((size_t)T_TOKENS * sizeof(int4));
  ushort* xb   = (ushort*)carve((size_t)T_TOKENS * HD * 2);
  ushort* w1b  = (ushort*)carve((size_t)NE * FD * HD * 2);
  ushort* w2b  = (ushort*)carve((size_t)NE * HD * FD * 2);
  ushort* Abuf = (ushort*)carve((size_t)T_TOKENS * 2 * FD * 2);  // compact GELU out, bf16
  float*  Y    = (float*)carve((size_t)T_TOKENS * 2 * HD * 4);   // gated FC2 rows, fp32

  hipMemsetAsync(counts, 0, NE * CSTRIDE * sizeof(int), stream);
  cvt_bf16<<<2048, 256, 0, stream>>>((const float4*)x, (ushort4*)xb, T_TOKENS * HD / 4);
  cvt_bf16<<<2048, 256, 0, stream>>>((const float4*)fc1w, (ushort4*)w1b, NE * FD * HD / 4);
  cvt_bf16<<<2048, 256, 0, stream>>>((const float4*)fc2w, (ushort4*)w2b, NE * HD * FD / 4);
  router_kernel<<<T_TOKENS / 64, 256, 0, stream>>>(x, rw, probs, topk, counts, bucket_tok,
                                                   bucket_w, tok_info);
  scan_kernel<<<1, 64, 0, stream>>>(counts, offsets);
  ffn_gemm<true><<<dim3(FD / BN, CAP / BM, NE), 256, 0, stream>>>(
      xb, w1b, fc1b, counts, offsets, bucket_tok, bucket_w, Abuf, nullptr, HD, FD);
  ffn_gemm<false><<<dim3(HD / BN, CAP / BM, NE), 256, 0, stream>>>(
      Abuf, w2b, fc2b, counts, offsets, bucket_tok, bucket_w, nullptr, Y, FD, HD);
  combine_kernel<<<T_TOKENS, 128, 0, stream>>>((const float4*)Y, tok_info, offsets, (float4*)out);
}

// Round 7
// 396.114 us; speedup vs baseline: 1.0946x; 1.0484x over previous
//
#include <hip/hip_runtime.h>

// Problem constants: B=4, S=2048 -> T=8192 tokens; H=512, F=2048, E=8, K=2.
#define T_TOKENS 8192
#define HD 512
#define FD 2048
#define NE 8
#define CAP 8192   // per-expert bucket capacity
#define CSTRIDE 32 // counter padding: one counter per 128B line

#define BM 128
#define BN 128
#define BK 32      // R3 shape: best measured GEMM (88 us). BK=64/BN=64 regressed (R5/R6).

typedef __attribute__((ext_vector_type(8))) short short8;   // 8 bf16 = 4 VGPRs
typedef __attribute__((ext_vector_type(4))) float f32x4;    // MFMA accumulator

__device__ __forceinline__ ushort f2bf(float f) {
  union { float f; unsigned u; } v; v.f = f;
  unsigned u = v.u;
  return (ushort)((u + 0x7fffu + ((u >> 16) & 1u)) >> 16);  // RNE
}

// async global->LDS, 16B per lane (wave-uniform base + lane*16).
__device__ __forceinline__ void gld16(const void* g, void* l) {
  __builtin_amdgcn_global_load_lds(
      (const __attribute__((address_space(1))) void*)g,
      (__attribute__((address_space(3))) void*)l, 16, 0, 0);
}

// ---------------- fused fp32 -> bf16 convert for BOTH weight tensors ----------------
__global__ void cvt_weights(const float4* __restrict__ w1, ushort4* __restrict__ w1o, int n1,
                            const float4* __restrict__ w2, ushort4* __restrict__ w2o, int n2) {
  int i = blockIdx.x * blockDim.x + threadIdx.x;
  int st = gridDim.x * blockDim.x;
  int nt = n1 + n2;
  for (; i < nt; i += st) {
    const float4* s; ushort4* d; int j;
    if (i < n1) { s = w1; d = w1o; j = i; } else { s = w2; d = w2o; j = i - n1; }
    float4 v = s[j];
    ushort4 o;
    o.x = f2bf(v.x); o.y = f2bf(v.y); o.z = f2bf(v.z); o.w = f2bf(v.w);
    d[j] = o;
  }
}

// ---------------- router: logits -> softmax -> top2 -> buckets (+ x->bf16) ----------
// R7: 16 lanes per token (4 tokens/wave, 16 tokens/block, 512 blocks = 2/CU).
// R2's 16-sequential-tokens-per-wave shape left half the CUs idle and ran the
// scalar section 1-of-64 lanes; this runs it 16-of-64 and is 8x more parallel.
// Also writes xb (bf16 x) as a side effect - kills the separate x-cvt kernel.
__global__ void router_kernel(const float* __restrict__ x, const float* __restrict__ rw,
                              ushort* __restrict__ xb,
                              float* __restrict__ probs_out, float* __restrict__ topk_out,
                              int* __restrict__ counts, int* __restrict__ bucket_tok,
                              float* __restrict__ bucket_w, int4* __restrict__ tok_info) {
  __shared__ int lcnt[NE];
  __shared__ int lbase[NE];
  __shared__ int ls_e0[16], ls_e1[16], ls_s0[16], ls_s1[16];
  __shared__ float ls_w0[16], ls_w1[16];

  int tid = threadIdx.x;
  int wave = tid >> 6, lane = tid & 63;
  int sub = lane >> 4, l16 = lane & 15;
  if (tid < NE) lcnt[tid] = 0;
  __syncthreads();

  int tbase = blockIdx.x * 16;
  int lt = wave * 4 + sub;
  int t = tbase + lt;

  float acc[NE];
#pragma unroll
  for (int e = 0; e < NE; e++) acc[e] = 0.f;
  const float* xr = x + (size_t)t * HD;
  ushort* xo = xb + (size_t)t * HD;
  for (int c = 0; c < HD; c += 16) {
    float xv = xr[c + l16];
    xo[c + l16] = f2bf(xv);
#pragma unroll
    for (int e = 0; e < NE; e++) acc[e] += xv * rw[e * HD + c + l16];
  }
  // reduce within 16-lane group
#pragma unroll
  for (int e = 0; e < NE; e++) {
#pragma unroll
    for (int s = 8; s > 0; s >>= 1) acc[e] += __shfl_xor(acc[e], s, 64);
  }
  // all 16 lanes now hold full logits; compute softmax redundantly
  float m = acc[0];
#pragma unroll
  for (int e = 1; e < NE; e++) m = fmaxf(m, acc[e]);
  float p[NE], s = 0.f;
#pragma unroll
  for (int e = 0; e < NE; e++) { p[e] = expf(acc[e] - m); s += p[e]; }
  float inv = 1.f / s;
#pragma unroll
  for (int e = 0; e < NE; e++) p[e] *= inv;
  if (l16 < NE) probs_out[(size_t)t * NE + l16] = p[l16];
  if (l16 == 0) {
    int i0 = 0;
#pragma unroll
    for (int e = 1; e < NE; e++) if (p[e] > p[i0]) i0 = e;
    int i1 = (i0 == 0) ? 1 : 0;
#pragma unroll
    for (int e = 0; e < NE; e++) if (e != i0 && p[e] > p[i1]) i1 = e;
    float r = 1.f / (p[i0] + p[i1] + 1e-9f);
    topk_out[(size_t)t * 2 + 0] = (float)i0;
    topk_out[(size_t)t * 2 + 1] = (float)i1;
    ls_e0[lt] = i0; ls_e1[lt] = i1;
    ls_w0[lt] = p[i0] * r; ls_w1[lt] = p[i1] * r;
    ls_s0[lt] = atomicAdd(&lcnt[i0], 1);
    ls_s1[lt] = atomicAdd(&lcnt[i1], 1);
  }
  __syncthreads();
  if (tid < NE)
    lbase[tid] = atomicAdd(&counts[tid * CSTRIDE], lcnt[tid]);
  __syncthreads();
  if (tid < 16) {
    int k = tid, tk = tbase + k;
    int e0 = ls_e0[k], e1 = ls_e1[k];
    int g0 = lbase[e0] + ls_s0[k];
    int g1 = lbase[e1] + ls_s1[k];
    bucket_tok[e0 * CAP + g0] = tk; bucket_w[e0 * CAP + g0] = ls_w0[k];
    bucket_tok[e1 * CAP + g1] = tk; bucket_w[e1 * CAP + g1] = ls_w1[k];
    tok_info[tk] = make_int4(e0, e1, g0, g1);
  }
}

__global__ void scan_kernel(const int* __restrict__ counts, int* __restrict__ offsets) {
  if (threadIdx.x == 0) {
    int o = 0;
#pragma unroll
    for (int e = 0; e < NE; e++) { offsets[e] = o; o += counts[e * CSTRIDE]; }
  }
}

// ---------------- grouped GEMM (bf16 MFMA 16x16x32), FC1 and FC2 ----------------
// R3 skeleton (best measured: 88 us/GEMM) + R5/R6's verified conflict-free
// kc-major LDS layout: chunk (kc,row) at byte (kc*128+row)*16, chunk index
// = u*256+tid (satisfies the DMA wave-uniform-base+lane*16 constraint);
// fragment reads are lane-consecutive 16B (0 conflict cycles vs R3's 4.3M).
// Plain __syncthreads K-loop: manual vmcnt pipelining regressed (R6, cf m139).
template <bool IS_FC1>
__global__ __launch_bounds__(256, 2)
void ffn_gemm(const ushort* __restrict__ Ab, const ushort* __restrict__ Bw,
              const float* __restrict__ bias, const int* __restrict__ counts,
              const int* __restrict__ offsets, const int* __restrict__ bucket_tok,
              const float* __restrict__ bucket_w, ushort* __restrict__ Aout,
              float* __restrict__ Yout, int KD, int ND) {
  int e = blockIdx.z;
  int cnt = counts[e * CSTRIDE];
  int m0 = blockIdx.y * BM;
  if (m0 >= cnt) return;
  int n0 = blockIdx.x * BN;
  int off = offsets[e];

  __shared__ alignas(16) ushort smem[10240];  // 20 KB: 16 KB staging, epilogue reuse
  ushort* As = smem;          // [kc][row][8] : 4096 ushorts
  ushort* Bs = smem + 4096;

  int tid = threadIdx.x;
  int wid = tid >> 6, lane = tid & 63;
  int wm = wid >> 1, wn = wid & 1;
  int q = lane >> 4, l16 = lane & 15;

  // staging: chunk c = u*256 + tid -> kc = u*2 + (tid>>7), row = tid&127
  int srow = tid & 127;
  int kc0 = tid >> 7;
  int mr = min(m0 + srow, cnt - 1);
  int arow = IS_FC1 ? bucket_tok[e * CAP + mr] : (off + mr);
  const ushort* ag = Ab + (size_t)arow * KD + kc0 * 8;
  const ushort* bg = Bw + ((size_t)e * ND + n0 + srow) * KD + kc0 * 8;
  ushort* lA = As + (size_t)tid * 8;
  ushort* lB = Bs + (size_t)tid * 8;

  f32x4 acc[4][4] = {};

  for (int k0 = 0; k0 < KD; k0 += BK) {
    gld16(ag + k0, lA);  gld16(ag + k0 + 16, lA + 2048);
    gld16(bg + k0, lB);  gld16(bg + k0 + 16, lB + 2048);
    __syncthreads();
    short8 af[4], bfr[4];
#pragma unroll
    for (int i = 0; i < 4; i++)
      af[i] = *(const short8*)&As[(q * BM + wm * 64 + i * 16 + l16) * 8];
#pragma unroll
    for (int j = 0; j < 4; j++)
      bfr[j] = *(const short8*)&Bs[(q * BN + wn * 64 + j * 16 + l16) * 8];
#pragma unroll
    for (int i = 0; i < 4; i++)
#pragma unroll
      for (int j = 0; j < 4; j++)
        acc[i][j] = __builtin_amdgcn_mfma_f32_16x16x32_bf16(af[i], bfr[j], acc[i][j], 0, 0, 0);
    __syncthreads();
  }

  // ---- epilogue through LDS (reuses smem) ----
  float bcol[4];
#pragma unroll
  for (int j = 0; j < 4; j++)
    bcol[j] = bias[(size_t)e * ND + n0 + wn * 64 + j * 16 + l16];

  if (IS_FC1) {
    ushort* Ct = smem;  // [32][136] bf16 = 8704 B
#pragma unroll
    for (int i = 0; i < 4; i++) {
      __syncthreads();
#pragma unroll
      for (int j = 0; j < 4; j++)
#pragma unroll
        for (int r = 0; r < 4; r++) {
          float v = acc[i][j][r] + bcol[j];
          float g = 0.5f * v * (1.0f + erff(v * 0.70710678118654752f));
          Ct[(wm * 16 + q * 4 + r) * 136 + wn * 64 + j * 16 + l16] = f2bf(g);
        }
      __syncthreads();
#pragma unroll
      for (int u = 0; u < 2; u++) {
        int c = tid + u * 256;            // 512 chunks of 8 bf16
        int ml = c >> 4, cc = c & 15;
        int gm = m0 + (ml >> 4) * 64 + i * 16 + (ml & 15);
        if (gm < cnt)
          *(uint4*)&Aout[(size_t)(off + gm) * ND + n0 + cc * 8] =
              *(const uint4*)&Ct[ml * 136 + cc * 8];
      }
    }
  } else {
    float* Ct = (float*)smem;  // [32][132] fp32 = 16896 B <= 20480
#pragma unroll
    for (int i = 0; i < 4; i++) {
      __syncthreads();
#pragma unroll
      for (int r = 0; r < 4; r++) {
        int gm = m0 + wm * 64 + i * 16 + q * 4 + r;
        float wgt = bucket_w[e * CAP + min(gm, cnt - 1)];
#pragma unroll
        for (int j = 0; j < 4; j++)
          Ct[(wm * 16 + q * 4 + r) * 132 + wn * 64 + j * 16 + l16] = wgt * (acc[i][j][r] + bcol[j]);
      }
      __syncthreads();
#pragma unroll
      for (int u = 0; u < 4; u++) {
        int c = tid + u * 256;            // 1024 chunks of 4 floats
        int ml = c >> 5, cc = c & 31;
        int gm = m0 + (ml >> 4) * 64 + i * 16 + (ml & 15);
        if (gm < cnt)
          *(float4*)&Yout[(size_t)(off + gm) * ND + n0 + cc * 4] =
              *(const float4*)&Ct[ml * 132 + cc * 4];
      }
    }
  }
}

// ---------------- combine: out[t] = Y[row(e0,s0)] + Y[row(e1,s1)] ----------------
__global__ void combine_kernel(const float4* __restrict__ Y, const int4* __restrict__ tok_info,
                               const int* __restrict__ offsets, float4* __restrict__ out) {
  int t = blockIdx.x;
  int4 ti = tok_info[t];
  int g0 = offsets[ti.x] + ti.z;
  int g1 = offsets[ti.y] + ti.w;
  int i = threadIdx.x;  // 128 threads, H/4 = 128 float4 per row
  float4 a = Y[(size_t)g0 * (HD / 4) + i];
  float4 b = Y[(size_t)g1 * (HD / 4) + i];
  out[(size_t)t * (HD / 4) + i] = make_float4(a.x + b.x, a.y + b.y, a.z + b.z, a.w + b.w);
}

extern "C" void kernel_launch(void* const* d_in, const int* in_sizes, int n_in,
                              void* d_out, int out_size, void* d_ws, size_t ws_size,
                              hipStream_t stream) {
  const float* x    = (const float*)d_in[0];
  const float* rw   = (const float*)d_in[1];
  const float* fc1w = (const float*)d_in[2];
  const float* fc1b = (const float*)d_in[3];
  const float* fc2w = (const float*)d_in[4];
  const float* fc2b = (const float*)d_in[5];

  float* out   = (float*)d_out;
  float* probs = out + (size_t)T_TOKENS * HD;
  float* topk  = probs + (size_t)T_TOKENS * NE;

  char* p = (char*)d_ws;
  auto carve = [&](size_t bytes) { char* r = p; p += (bytes + 255) & ~(size_t)255; return r; };
  int*    counts     = (int*)carve(NE * CSTRIDE * sizeof(int));
  int*    offsets    = (int*)carve(NE * sizeof(int));
  int*    bucket_tok = (int*)carve((size_t)NE * CAP * sizeof(int));
  float*  bucket_w   = (float*)carve((size_t)NE * CAP * sizeof(float));
  int4*   tok_info   = (int4*)carve((size_t)T_TOKENS * sizeof(int4));
  ushort* xb   = (ushort*)carve((size_t)T_TOKENS * HD * 2);
  ushort* w1b  = (ushort*)carve((size_t)NE * FD * HD * 2);
  ushort* w2b  = (ushort*)carve((size_t)NE * HD * FD * 2);
  ushort* Abuf = (ushort*)carve((size_t)T_TOKENS * 2 * FD * 2);  // compact GELU out, bf16
  float*  Y    = (float*)carve((size_t)T_TOKENS * 2 * HD * 4);   // gated FC2 rows, fp32

  hipMemsetAsync(counts, 0, NE * CSTRIDE * sizeof(int), stream);
  cvt_weights<<<2048, 256, 0, stream>>>((const float4*)fc1w, (ushort4*)w1b, NE * FD * HD / 4,
                                        (const float4*)fc2w, (ushort4*)w2b, NE * HD * FD / 4);
  router_kernel<<<T_TOKENS / 16, 256, 0, stream>>>(x, rw, xb, probs, topk, counts, bucket_tok,
                                                   bucket_w, tok_info);
  scan_kernel<<<1, 64, 0, stream>>>(counts, offsets);
  ffn_gemm<true><<<dim3(FD / BN, CAP / BM, NE), 256, 0, stream>>>(
      xb, w1b, fc1b, counts, offsets, bucket_tok, bucket_w, Abuf, nullptr, HD, FD);
  ffn_gemm<false><<<dim3(HD / BN, CAP / BM, NE), 256, 0, stream>>>(
      Abuf, w2b, fc2b, counts, offsets, bucket_tok, bucket_w, nullptr, Y, FD, HD);
  combine_kernel<<<T_TOKENS, 128, 0, stream>>>((const float4*)Y, tok_info, offsets, (float4*)out);
}

// Round 8
// 368.862 us; speedup vs baseline: 1.1755x; 1.0739x over previous
//
#include <hip/hip_runtime.h>

// Problem constants: B=4, S=2048 -> T=8192 tokens; H=512, F=2048, E=8, K=2.
#define T_TOKENS 8192
#define HD 512
#define FD 2048
#define NE 8
#define CAP 8192   // per-expert bucket capacity
#define CSTRIDE 32 // counter padding: one counter per 128B line

// R8: 256x256 tiles, 512 threads, BK=32. GEMMs are staging-BW-bound
// (R3..R7 evidence): staged bytes = grid*(BM+BN)*K*2 -> 256-tiles halve it.

typedef __attribute__((ext_vector_type(8))) short short8;   // 8 bf16 = 4 VGPRs
typedef __attribute__((ext_vector_type(4))) float f32x4;    // MFMA accumulator

__device__ __forceinline__ ushort f2bf(float f) {
  union { float f; unsigned u; } v; v.f = f;
  unsigned u = v.u;
  return (ushort)((u + 0x7fffu + ((u >> 16) & 1u)) >> 16);  // RNE
}

// async global->LDS, 16B per lane (wave-uniform base + lane*16).
__device__ __forceinline__ void gld16(const void* g, void* l) {
  __builtin_amdgcn_global_load_lds(
      (const __attribute__((address_space(1))) void*)g,
      (__attribute__((address_space(3))) void*)l, 16, 0, 0);
}

// ---------------- weight convert + TILE: write the exact LDS staging image ------
// Tiled layout: tile (e, nb, kt) = 1024 chunks of 16B; chunk c = kc*256+row holds
// W[e][nb*256+row][kt*32 + kc*8 .. +8] as bf16. GEMM B-staging then reads the
// tile linearly (perfect coalescing) and LDS fragment reads are lane-consecutive.
__global__ void cvt_weights_tiled(const float* __restrict__ w1, ushort* __restrict__ w1t,
                                  const float* __restrict__ w2, ushort* __restrict__ w2t) {
  int g = blockIdx.x * blockDim.x + threadIdx.x;   // 2*262144 threads total
  const float* W; ushort* Wt; int n, kt, e, N, KT;
  int t = g;
  if (t < 8 * 16 * 2048) {        // w1: E=8, KT=16 (K=512), N=2048
    W = w1; Wt = w1t; n = t & 2047; kt = (t >> 11) & 15; e = t >> 15; N = 2048; KT = 16;
  } else {                        // w2: E=8, KT=64 (K=2048), N=512
    t -= 8 * 16 * 2048;
    W = w2; Wt = w2t; n = t & 511; kt = (t >> 9) & 63; e = t >> 15; N = 512; KT = 64;
  }
  int K = KT * 32;
  const float* src = W + ((size_t)e * N + n) * K + kt * 32;   // full 128B line/thread
  int nb = n >> 8, row = n & 255;
  ushort* dst = Wt + (((size_t)e * (N / 256) + nb) * KT + kt) * 8192 + row * 8;
#pragma unroll
  for (int kc = 0; kc < 4; kc++) {
    float4 a = *(const float4*)(src + kc * 8);
    float4 b = *(const float4*)(src + kc * 8 + 4);
    ushort4 o1, o2;
    o1.x = f2bf(a.x); o1.y = f2bf(a.y); o1.z = f2bf(a.z); o1.w = f2bf(a.w);
    o2.x = f2bf(b.x); o2.y = f2bf(b.y); o2.z = f2bf(b.z); o2.w = f2bf(b.w);
    *(ushort4*)(dst + kc * 2048) = o1;          // lanes: row-consecutive 16B ✓
    *(ushort4*)(dst + kc * 2048 + 4) = o2;
  }
}

// ---------------- router: logits -> softmax -> top2 -> buckets (+ x->bf16) ----------
__global__ void router_kernel(const float* __restrict__ x, const float* __restrict__ rw,
                              ushort* __restrict__ xb,
                              float* __restrict__ probs_out, float* __restrict__ topk_out,
                              int* __restrict__ counts, int* __restrict__ bucket_tok,
                              float* __restrict__ bucket_w, int4* __restrict__ tok_info) {
  __shared__ int lcnt[NE];
  __shared__ int lbase[NE];
  __shared__ int ls_e0[16], ls_e1[16], ls_s0[16], ls_s1[16];
  __shared__ float ls_w0[16], ls_w1[16];

  int tid = threadIdx.x;
  int wave = tid >> 6, lane = tid & 63;
  int sub = lane >> 4, l16 = lane & 15;
  if (tid < NE) lcnt[tid] = 0;
  __syncthreads();

  int tbase = blockIdx.x * 16;
  int lt = wave * 4 + sub;
  int t = tbase + lt;

  float acc[NE];
#pragma unroll
  for (int e = 0; e < NE; e++) acc[e] = 0.f;
  const float* xr = x + (size_t)t * HD;
  ushort* xo = xb + (size_t)t * HD;
  for (int c = 0; c < HD; c += 16) {
    float xv = xr[c + l16];
    xo[c + l16] = f2bf(xv);
#pragma unroll
    for (int e = 0; e < NE; e++) acc[e] += xv * rw[e * HD + c + l16];
  }
#pragma unroll
  for (int e = 0; e < NE; e++) {
#pragma unroll
    for (int s = 8; s > 0; s >>= 1) acc[e] += __shfl_xor(acc[e], s, 64);
  }
  float m = acc[0];
#pragma unroll
  for (int e = 1; e < NE; e++) m = fmaxf(m, acc[e]);
  float p[NE], s = 0.f;
#pragma unroll
  for (int e = 0; e < NE; e++) { p[e] = expf(acc[e] - m); s += p[e]; }
  float inv = 1.f / s;
#pragma unroll
  for (int e = 0; e < NE; e++) p[e] *= inv;
  if (l16 < NE) probs_out[(size_t)t * NE + l16] = p[l16];
  if (l16 == 0) {
    int i0 = 0;
#pragma unroll
    for (int e = 1; e < NE; e++) if (p[e] > p[i0]) i0 = e;
    int i1 = (i0 == 0) ? 1 : 0;
#pragma unroll
    for (int e = 0; e < NE; e++) if (e != i0 && p[e] > p[i1]) i1 = e;
    float r = 1.f / (p[i0] + p[i1] + 1e-9f);
    topk_out[(size_t)t * 2 + 0] = (float)i0;
    topk_out[(size_t)t * 2 + 1] = (float)i1;
    ls_e0[lt] = i0; ls_e1[lt] = i1;
    ls_w0[lt] = p[i0] * r; ls_w1[lt] = p[i1] * r;
    ls_s0[lt] = atomicAdd(&lcnt[i0], 1);
    ls_s1[lt] = atomicAdd(&lcnt[i1], 1);
  }
  __syncthreads();
  if (tid < NE)
    lbase[tid] = atomicAdd(&counts[tid * CSTRIDE], lcnt[tid]);
  __syncthreads();
  if (tid < 16) {
    int k = tid, tk = tbase + k;
    int e0 = ls_e0[k], e1 = ls_e1[k];
    int g0 = lbase[e0] + ls_s0[k];
    int g1 = lbase[e1] + ls_s1[k];
    bucket_tok[e0 * CAP + g0] = tk; bucket_w[e0 * CAP + g0] = ls_w0[k];
    bucket_tok[e1 * CAP + g1] = tk; bucket_w[e1 * CAP + g1] = ls_w1[k];
    tok_info[tk] = make_int4(e0, e1, g0, g1);
  }
}

__global__ void scan_kernel(const int* __restrict__ counts, int* __restrict__ offsets) {
  if (threadIdx.x == 0) {
    int o = 0;
#pragma unroll
    for (int e = 0; e < NE; e++) { offsets[e] = o; o += counts[e * CSTRIDE]; }
  }
}

// ---------------- grouped GEMM 256x256, bf16 MFMA 16x16x32, 512 threads ----------
// A: gld16, R3-proven [row][kseg] layout (4 lanes cover a 64B row slab - coalesced).
// B: gld16 from PRE-TILED weights: global reads fully sequential (1KB/wave-issue),
//    LDS image is kc-major -> fragment reads lane-consecutive, conflict-free.
// 8 waves as 2(m) x 4(n): per wave 128m x 64n, acc[8][4] (128 VGPRs).
template <bool IS_FC1>
__global__ __launch_bounds__(512, 2)
void ffn_gemm(const ushort* __restrict__ Ab, const ushort* __restrict__ Bt,
              const float* __restrict__ bias, const int* __restrict__ counts,
              const int* __restrict__ offsets, const int* __restrict__ bucket_tok,
              const float* __restrict__ bucket_w, ushort* __restrict__ Aout,
              float* __restrict__ Yout, int KD, int ND) {
  int e = blockIdx.z;
  int cnt = counts[e * CSTRIDE];
  int m0 = blockIdx.y * 256;
  if (m0 >= cnt) return;
  int nb = blockIdx.x;
  int n0 = nb * 256;
  int off = offsets[e];
  int NB = ND / 256, KT = KD / 32;

  __shared__ alignas(16) ushort smem[16640];  // 33.3 KB (32K staging; fp32 epilogue tile)
  ushort* As = smem;            // 16 KB: 1024 chunks, [row][kseg]
  ushort* Bs = smem + 8192;     // 16 KB: 1024 chunks, kc-major (pre-tiled image)

  int tid = threadIdx.x;
  int wid = tid >> 6, lane = tid & 63;
  int wm = wid >> 2, wn = wid & 3;
  int q = lane >> 4, l16 = lane & 15;

  // A staging: chunk c = tid + u*512 -> row = c>>2 (0..255), kseg = c&3
  const ushort* ag[2];
#pragma unroll
  for (int u = 0; u < 2; u++) {
    int c = tid + u * 512;
    int row = c >> 2, ks = c & 3;
    int mr = min(m0 + row, cnt - 1);
    int arow = IS_FC1 ? bucket_tok[e * CAP + mr] : (off + mr);
    ag[u] = Ab + (size_t)arow * KD + ks * 8;
  }
  // B staging: tile (e,nb,kt) is 8192 ushorts, read linearly
  const ushort* bg = Bt + ((size_t)e * NB + nb) * KT * 8192 + (size_t)tid * 8;

  f32x4 acc[8][4] = {};

  for (int kt = 0; kt < KT; kt++) {
#pragma unroll
    for (int u = 0; u < 2; u++)
      gld16(ag[u] + kt * 32, As + (size_t)(tid + u * 512) * 8);
#pragma unroll
    for (int u = 0; u < 2; u++)
      gld16(bg + (size_t)kt * 8192 + u * 4096, Bs + (size_t)(tid + u * 512) * 8);
    __syncthreads();
    short8 af[8], bfr[4];
#pragma unroll
    for (int i = 0; i < 8; i++) {
      int m = wm * 128 + i * 16 + l16;
      af[i] = *(const short8*)&As[(m * 4 + q) * 8];
    }
#pragma unroll
    for (int j = 0; j < 4; j++) {
      int n = wn * 64 + j * 16 + l16;
      bfr[j] = *(const short8*)&Bs[(q * 256 + n) * 8];
    }
#pragma unroll
    for (int i = 0; i < 8; i++)
#pragma unroll
      for (int j = 0; j < 4; j++)
        acc[i][j] = __builtin_amdgcn_mfma_f32_16x16x32_bf16(af[i], bfr[j], acc[i][j], 0, 0, 0);
    __syncthreads();
  }

  // ---- epilogue through LDS: 8 rounds of 32 rows x 256 cols ----
  float bcol[4];
#pragma unroll
  for (int j = 0; j < 4; j++)
    bcol[j] = bias[(size_t)e * ND + n0 + wn * 64 + j * 16 + l16];

  if (IS_FC1) {
    ushort* Ct = smem;  // [32][264] bf16 = 16.5 KB
#pragma unroll
    for (int i = 0; i < 8; i++) {
      __syncthreads();
#pragma unroll
      for (int j = 0; j < 4; j++)
#pragma unroll
        for (int r = 0; r < 4; r++) {
          float v = acc[i][j][r] + bcol[j];
          float g = 0.5f * v * (1.0f + erff(v * 0.70710678118654752f));
          Ct[(wm * 16 + q * 4 + r) * 264 + wn * 64 + j * 16 + l16] = f2bf(g);
        }
      __syncthreads();
#pragma unroll
      for (int u = 0; u < 2; u++) {
        int c = tid + u * 512;            // 1024 chunks of 8 bf16 (32 rows x 32 cc)
        int ml = c >> 5, cc = c & 31;
        int gm = m0 + (ml >> 4) * 128 + i * 16 + (ml & 15);
        if (gm < cnt)
          *(uint4*)&Aout[(size_t)(off + gm) * ND + n0 + cc * 8] =
              *(const uint4*)&Ct[ml * 264 + cc * 8];
      }
    }
  } else {
    float* Ct = (float*)smem;  // [32][260] fp32 = 33.3 KB
#pragma unroll
    for (int i = 0; i < 8; i++) {
      __syncthreads();
#pragma unroll
      for (int r = 0; r < 4; r++) {
        int gm = m0 + wm * 128 + i * 16 + q * 4 + r;
        float wgt = bucket_w[e * CAP + min(gm, cnt - 1)];
#pragma unroll
        for (int j = 0; j < 4; j++)
          Ct[(wm * 16 + q * 4 + r) * 260 + wn * 64 + j * 16 + l16] = wgt * (acc[i][j][r] + bcol[j]);
      }
      __syncthreads();
#pragma unroll
      for (int u = 0; u < 4; u++) {
        int c = tid + u * 512;            // 2048 chunks of 4 floats (32 rows x 64 cc)
        int ml = c >> 6, cc = c & 63;
        int gm = m0 + (ml >> 4) * 128 + i * 16 + (ml & 15);
        if (gm < cnt)
          *(float4*)&Yout[(size_t)(off + gm) * ND + n0 + cc * 4] =
              *(const float4*)&Ct[ml * 260 + cc * 4];
      }
    }
  }
}

// ---------------- combine: out[t] = Y[row(e0,s0)] + Y[row(e1,s1)] ----------------
__global__ void combine_kernel(const float4* __restrict__ Y, const int4* __restrict__ tok_info,
                               const int* __restrict__ offsets, float4* __restrict__ out) {
  int t = blockIdx.x;
  int4 ti = tok_info[t];
  int g0 = offsets[ti.x] + ti.z;
  int g1 = offsets[ti.y] + ti.w;
  int i = threadIdx.x;  // 128 threads, H/4 = 128 float4 per row
  float4 a = Y[(size_t)g0 * (HD / 4) + i];
  float4 b = Y[(size_t)g1 * (HD / 4) + i];
  out[(size_t)t * (HD / 4) + i] = make_float4(a.x + b.x, a.y + b.y, a.z + b.z, a.w + b.w);
}

extern "C" void kernel_launch(void* const* d_in, const int* in_sizes, int n_in,
                              void* d_out, int out_size, void* d_ws, size_t ws_size,
                              hipStream_t stream) {
  const float* x    = (const float*)d_in[0];
  const float* rw   = (const float*)d_in[1];
  const float* fc1w = (const float*)d_in[2];
  const float* fc1b = (const float*)d_in[3];
  const float* fc2w = (const float*)d_in[4];
  const float* fc2b = (const float*)d_in[5];

  float* out   = (float*)d_out;
  float* probs = out + (size_t)T_TOKENS * HD;
  float* topk  = probs + (size_t)T_TOKENS * NE;

  char* p = (char*)d_ws;
  auto carve = [&](size_t bytes) { char* r = p; p += (bytes + 255) & ~(size_t)255; return r; };
  int*    counts     = (int*)carve(NE * CSTRIDE * sizeof(int));
  int*    offsets    = (int*)carve(NE * sizeof(int));
  int*    bucket_tok = (int*)carve((size_t)NE * CAP * sizeof(int));
  float*  bucket_w   = (float*)carve((size_t)NE * CAP * sizeof(float));
  int4*   tok_info   = (int4*)carve((size_t)T_TOKENS * sizeof(int4));
  ushort* xb   = (ushort*)carve((size_t)T_TOKENS * HD * 2);
  ushort* w1t  = (ushort*)carve((size_t)NE * FD * HD * 2);
  ushort* w2t  = (ushort*)carve((size_t)NE * HD * FD * 2);
  ushort* Abuf = (ushort*)carve((size_t)T_TOKENS * 2 * FD * 2);  // compact GELU out, bf16
  float*  Y    = (float*)carve((size_t)T_TOKENS * 2 * HD * 4);   // gated FC2 rows, fp32

  hipMemsetAsync(counts, 0, NE * CSTRIDE * sizeof(int), stream);
  cvt_weights_tiled<<<2048, 256, 0, stream>>>(fc1w, w1t, fc2w, w2t);
  router_kernel<<<T_TOKENS / 16, 256, 0, stream>>>(x, rw, xb, probs, topk, counts, bucket_tok,
                                                   bucket_w, tok_info);
  scan_kernel<<<1, 64, 0, stream>>>(counts, offsets);
  ffn_gemm<true><<<dim3(FD / 256, CAP / 256, NE), 512, 0, stream>>>(
      xb, w1t, fc1b, counts, offsets, bucket_tok, bucket_w, Abuf, nullptr, HD, FD);
  ffn_gemm<false><<<dim3(HD / 256, CAP / 256, NE), 512, 0, stream>>>(
      Abuf, w2t, fc2b, counts, offsets, bucket_tok, bucket_w, nullptr, Y, FD, HD);
  combine_kernel<<<T_TOKENS, 128, 0, stream>>>((const float4*)Y, tok_info, offsets, (float4*)out);
}